// Round 1
// 1456.338 us; speedup vs baseline: 3.5099x; 3.5099x over previous
//
#include <hip/hip_runtime.h>
#include <cstddef>

#define T_LEN 4096
#define EMB 768
#define NH 12
#define HD 64
#define WIN 512

// ---------------- GEMM f32: C[M,N] = A[M,K] @ B[K,N], row-major.
__global__ __launch_bounds__(256) void gemm_f32_64x64(const float* __restrict__ A,
                                                      const float* __restrict__ B,
                                                      float* __restrict__ C,
                                                      int M, int N, int K) {
    __shared__ float As[16][68];
    __shared__ float Bs[16][68];
    const int tid = threadIdx.x;
    const int bm = blockIdx.y * 64;
    const int bn = blockIdx.x * 64;
    const int tm = (tid >> 4) << 2;
    const int tn = (tid & 15) << 2;

    const int lm  = tid >> 2;
    const int lk  = (tid & 3) << 2;
    const int bkr = tid >> 4;
    const int bnc = (tid & 15) << 2;

    float acc[4][4] = {};

    for (int k0 = 0; k0 < K; k0 += 16) {
        float4 a4 = *(const float4*)&A[(size_t)(bm + lm) * K + k0 + lk];
        As[lk + 0][lm] = a4.x;
        As[lk + 1][lm] = a4.y;
        As[lk + 2][lm] = a4.z;
        As[lk + 3][lm] = a4.w;
        *(float4*)&Bs[bkr][bnc] = *(const float4*)&B[(size_t)(k0 + bkr) * N + bn + bnc];
        __syncthreads();
#pragma unroll
        for (int k = 0; k < 16; ++k) {
            float4 av = *(float4*)&As[k][tm];
            float4 bv = *(float4*)&Bs[k][tn];
            acc[0][0] += av.x * bv.x; acc[0][1] += av.x * bv.y; acc[0][2] += av.x * bv.z; acc[0][3] += av.x * bv.w;
            acc[1][0] += av.y * bv.x; acc[1][1] += av.y * bv.y; acc[1][2] += av.y * bv.z; acc[1][3] += av.y * bv.w;
            acc[2][0] += av.z * bv.x; acc[2][1] += av.z * bv.y; acc[2][2] += av.z * bv.z; acc[2][3] += av.z * bv.w;
            acc[3][0] += av.w * bv.x; acc[3][1] += av.w * bv.y; acc[3][2] += av.w * bv.z; acc[3][3] += av.w * bv.w;
        }
        __syncthreads();
    }
#pragma unroll
    for (int i = 0; i < 4; ++i) {
        float4 cv = make_float4(acc[i][0], acc[i][1], acc[i][2], acc[i][3]);
        *(float4*)&C[(size_t)(bm + tm + i) * N + bn + tn] = cv;
    }
}

// ---------------- discoverability bias: d[h][t] = K_h[t]·u_h − mean
__global__ __launch_bounds__(256) void dbias_kernel(const float* __restrict__ K,
                                                    const float* __restrict__ u,
                                                    float* __restrict__ d_bias) {
    const int h = blockIdx.x;
    const int tid = threadIdx.x;
    __shared__ __align__(16) float us[HD];
    __shared__ float dr[T_LEN];
    __shared__ float red[256];
    if (tid < HD) us[tid] = u[h * HD + tid];
    __syncthreads();
    const float4* u4 = (const float4*)us;
    float lsum = 0.f;
    for (int t = tid; t < T_LEN; t += 256) {
        const float4* Kp = (const float4*)&K[(size_t)t * EMB + h * HD];
        float acc = 0.f;
#pragma unroll
        for (int i = 0; i < HD / 4; ++i) {
            float4 k4 = Kp[i];
            float4 uu = u4[i];
            acc += k4.x * uu.x + k4.y * uu.y + k4.z * uu.z + k4.w * uu.w;
        }
        dr[t] = acc;
        lsum += acc;
    }
    red[tid] = lsum;
    __syncthreads();
    for (int off = 128; off > 0; off >>= 1) {
        if (tid < off) red[tid] += red[tid + off];
        __syncthreads();
    }
    const float mean = red[0] * (1.0f / (float)T_LEN);
    __syncthreads();
    for (int t = tid; t < T_LEN; t += 256) {
        d_bias[h * T_LEN + t] = dr[t] - mean;
    }
}

// ---------------- tiled banded attention, flash-style online softmax.
// One block per (64-row t-tile, head). 16x16 threads, 4x4 per-thread register tiles.
// Writes RAW logits into the band region of attn (normalized later by attn_norm_kernel),
// accumulates ctx via P@V with online rescaling, stores per-row max + 1/den.
__global__ __launch_bounds__(256) void attn_band_kernel(const float* __restrict__ Q,
                                                        const float* __restrict__ K,
                                                        const float* __restrict__ V,
                                                        const float* __restrict__ d_bias,
                                                        const float* __restrict__ gates,
                                                        float* __restrict__ attn,
                                                        float* __restrict__ ctx,
                                                        float* __restrict__ row_max,
                                                        float* __restrict__ row_invden) {
    const int t0  = blockIdx.x << 6;
    const int h   = blockIdx.y;
    const int tid = threadIdx.x;
    const int tm  = (tid >> 4) << 2;   // row base within tile (0..60)
    const int tn4 = (tid & 15) << 2;   // col base within chunk (0..60)
    const int lm  = tid >> 2;          // staging: row 0..63
    const int lk  = (tid & 3) << 2;    // staging: k base 0..12

    __shared__ __align__(16) float QT[64][68];  // Q[t0+m][k] -> QT[k][m]
    __shared__ __align__(16) float KT[64][68];  // K[t0+m][k] -> KT[k][m]
    __shared__ __align__(16) float Cc[64][68];  // chunk staging: Kc / Qc / P (time-shared)
    __shared__ __align__(16) float Vc[64][64];  // V[s0+k][d] row-major

    // per-head gate softmax (fold 1/sqrt(64) into w_std/w_rec)
    const float g0 = gates[h * 3 + 0];
    const float g1 = gates[h * 3 + 1];
    const float g2 = gates[h * 3 + 2];
    const float gm = fmaxf(g0, fmaxf(g1, g2));
    const float e0 = __expf(g0 - gm), e1 = __expf(g1 - gm), e2 = __expf(g2 - gm);
    const float gi = 1.0f / (e0 + e1 + e2);
    const float w_std = e0 * gi * 0.125f;
    const float w_rec = e1 * gi * 0.125f;
    const float w_disc = e2 * gi;

    // stage this tile's Q and K rows, transposed to [k][m]
    {
        const float* Qp = Q + (size_t)(t0 + lm) * EMB + h * HD + lk;
        const float* Kp = K + (size_t)(t0 + lm) * EMB + h * HD + lk;
#pragma unroll
        for (int it = 0; it < 4; ++it) {
            float4 a = *(const float4*)(Qp + 16 * it);
            QT[lk + 16 * it + 0][lm] = a.x;
            QT[lk + 16 * it + 1][lm] = a.y;
            QT[lk + 16 * it + 2][lm] = a.z;
            QT[lk + 16 * it + 3][lm] = a.w;
            float4 b = *(const float4*)(Kp + 16 * it);
            KT[lk + 16 * it + 0][lm] = b.x;
            KT[lk + 16 * it + 1][lm] = b.y;
            KT[lk + 16 * it + 2][lm] = b.z;
            KT[lk + 16 * it + 3][lm] = b.w;
        }
    }

    const int s_base = (t0 - WIN > 0) ? (t0 - WIN) : 0;
    const int nch = ((t0 + 64) - s_base) >> 6;   // <= 9 chunks

    float rm[4], rden[4], acc[4][4];
#pragma unroll
    for (int i = 0; i < 4; ++i) {
        rm[i] = -1e30f;
        rden[i] = 0.f;
#pragma unroll
        for (int j = 0; j < 4; ++j) acc[i][j] = 0.f;
    }

    for (int c = 0; c < nch; ++c) {
        const int s0 = s_base + (c << 6);
        __syncthreads();   // previous chunk's PV reads of Cc/Vc done; QT/KT ready on c==0
        // stage K chunk (transposed) and V chunk (row-major)
        {
            const float* Kp = K + (size_t)(s0 + lm) * EMB + h * HD + lk;
            const float* Vp = V + (size_t)(s0 + lm) * EMB + h * HD + lk;
#pragma unroll
            for (int it = 0; it < 4; ++it) {
                float4 b = *(const float4*)(Kp + 16 * it);
                Cc[lk + 16 * it + 0][lm] = b.x;
                Cc[lk + 16 * it + 1][lm] = b.y;
                Cc[lk + 16 * it + 2][lm] = b.z;
                Cc[lk + 16 * it + 3][lm] = b.w;
                *(float4*)&Vc[lm][lk + 16 * it] = *(const float4*)(Vp + 16 * it);
            }
        }
        __syncthreads();

        // M1[i][j] = Q[t0+tm+i] . K[s0+tn4+j]
        float m1[4][4] = {};
#pragma unroll 16
        for (int k = 0; k < 64; ++k) {
            float4 av = *(const float4*)&QT[k][tm];
            float4 bv = *(const float4*)&Cc[k][tn4];
            m1[0][0] += av.x * bv.x; m1[0][1] += av.x * bv.y; m1[0][2] += av.x * bv.z; m1[0][3] += av.x * bv.w;
            m1[1][0] += av.y * bv.x; m1[1][1] += av.y * bv.y; m1[1][2] += av.y * bv.z; m1[1][3] += av.y * bv.w;
            m1[2][0] += av.z * bv.x; m1[2][1] += av.z * bv.y; m1[2][2] += av.z * bv.z; m1[2][3] += av.z * bv.w;
            m1[3][0] += av.w * bv.x; m1[3][1] += av.w * bv.y; m1[3][2] += av.w * bv.z; m1[3][3] += av.w * bv.w;
        }
        __syncthreads();
        // stage Q chunk (transposed) into Cc
        {
            const float* Qp2 = Q + (size_t)(s0 + lm) * EMB + h * HD + lk;
#pragma unroll
            for (int it = 0; it < 4; ++it) {
                float4 b = *(const float4*)(Qp2 + 16 * it);
                Cc[lk + 16 * it + 0][lm] = b.x;
                Cc[lk + 16 * it + 1][lm] = b.y;
                Cc[lk + 16 * it + 2][lm] = b.z;
                Cc[lk + 16 * it + 3][lm] = b.w;
            }
        }
        __syncthreads();

        // M2[i][j] = K[t0+tm+i] . Q[s0+tn4+j]   (the recurrence/transpose term)
        float m2[4][4] = {};
#pragma unroll 16
        for (int k = 0; k < 64; ++k) {
            float4 av = *(const float4*)&KT[k][tm];
            float4 bv = *(const float4*)&Cc[k][tn4];
            m2[0][0] += av.x * bv.x; m2[0][1] += av.x * bv.y; m2[0][2] += av.x * bv.z; m2[0][3] += av.x * bv.w;
            m2[1][0] += av.y * bv.x; m2[1][1] += av.y * bv.y; m2[1][2] += av.y * bv.z; m2[1][3] += av.y * bv.w;
            m2[2][0] += av.z * bv.x; m2[2][1] += av.z * bv.y; m2[2][2] += av.z * bv.z; m2[2][3] += av.z * bv.w;
            m2[3][0] += av.w * bv.x; m2[3][1] += av.w * bv.y; m2[3][2] += av.w * bv.z; m2[3][3] += av.w * bv.w;
        }

        // logits + band mask + raw store + online softmax state
        const float4 db = *(const float4*)&d_bias[h * T_LEN + s0 + tn4];
        float l[4][4];
#pragma unroll
        for (int i = 0; i < 4; ++i) {
            const int t = t0 + tm + i;
            const float dbv[4] = {db.x, db.y, db.z, db.w};
#pragma unroll
            for (int j = 0; j < 4; ++j) {
                const int s = s0 + tn4 + j;
                float lv = w_std * m1[i][j] + w_rec * m2[i][j] + w_disc * dbv[j];
                const bool valid = (s <= t) && (s >= t - WIN);
                l[i][j] = valid ? lv : -1e30f;
            }
            *(float4*)&attn[((size_t)(h * T_LEN + t)) * T_LEN + s0 + tn4] =
                make_float4(l[i][0], l[i][1], l[i][2], l[i][3]);
        }
        // chunk row max across the 16 lanes owning each row
        float cmx[4];
#pragma unroll
        for (int i = 0; i < 4; ++i)
            cmx[i] = fmaxf(fmaxf(l[i][0], l[i][1]), fmaxf(l[i][2], l[i][3]));
#pragma unroll
        for (int off = 1; off < 16; off <<= 1) {
#pragma unroll
            for (int i = 0; i < 4; ++i) cmx[i] = fmaxf(cmx[i], __shfl_xor(cmx[i], off));
        }
        // online update: rescale den/ctx, l -> p
        float cs[4];
#pragma unroll
        for (int i = 0; i < 4; ++i) {
            const float nm = fmaxf(rm[i], cmx[i]);
            const float f = __expf(rm[i] - nm);
            float s = 0.f;
#pragma unroll
            for (int j = 0; j < 4; ++j) {
                const float p = __expf(l[i][j] - nm);
                l[i][j] = p;
                s += p;
            }
            cs[i] = s;
            rm[i] = nm;
            rden[i] *= f;
#pragma unroll
            for (int j = 0; j < 4; ++j) acc[i][j] *= f;
        }
#pragma unroll
        for (int off = 1; off < 16; off <<= 1) {
#pragma unroll
            for (int i = 0; i < 4; ++i) cs[i] += __shfl_xor(cs[i], off);
        }
#pragma unroll
        for (int i = 0; i < 4; ++i) rden[i] += cs[i];

        __syncthreads();   // all M2 reads of Cc complete
        // scatter P into Cc as [k][m]
#pragma unroll
        for (int i = 0; i < 4; ++i)
#pragma unroll
            for (int j = 0; j < 4; ++j)
                Cc[tn4 + j][tm + i] = l[i][j];
        __syncthreads();

        // ctx += P @ V
#pragma unroll 16
        for (int k = 0; k < 64; ++k) {
            float4 av = *(const float4*)&Cc[k][tm];
            float4 bv = *(const float4*)&Vc[k][tn4];
            acc[0][0] += av.x * bv.x; acc[0][1] += av.x * bv.y; acc[0][2] += av.x * bv.z; acc[0][3] += av.x * bv.w;
            acc[1][0] += av.y * bv.x; acc[1][1] += av.y * bv.y; acc[1][2] += av.y * bv.z; acc[1][3] += av.y * bv.w;
            acc[2][0] += av.z * bv.x; acc[2][1] += av.z * bv.y; acc[2][2] += av.z * bv.z; acc[2][3] += av.z * bv.w;
            acc[3][0] += av.w * bv.x; acc[3][1] += av.w * bv.y; acc[3][2] += av.w * bv.z; acc[3][3] += av.w * bv.w;
        }
    }

    // epilogue: ctx and per-row stats
#pragma unroll
    for (int i = 0; i < 4; ++i) {
        const float idv = 1.0f / rden[i];
        *(float4*)&ctx[(size_t)(t0 + tm + i) * EMB + h * HD + tn4] =
            make_float4(acc[i][0] * idv, acc[i][1] * idv, acc[i][2] * idv, acc[i][3] * idv);
        if ((tid & 15) == 0) {
            row_max[h * T_LEN + t0 + tm + i] = rm[i];
            row_invden[h * T_LEN + t0 + tm + i] = idv;
        }
    }
}

// ---------------- normalize band + zero-fill full attn rows (streaming, write-BW-bound)
__global__ __launch_bounds__(256) void attn_norm_kernel(float* __restrict__ attn,
                                                        const float* __restrict__ row_max,
                                                        const float* __restrict__ row_invden) {
    const int t = blockIdx.x;
    const int h = blockIdx.y;
    const float m   = row_max[h * T_LEN + t];
    const float idv = row_invden[h * T_LEN + t];
    float* arow = attn + ((size_t)(h * T_LEN + t)) * T_LEN;
    const int bl = (t - WIN > 0) ? (t - WIN) : 0;
    for (int i4 = threadIdx.x << 2; i4 < T_LEN; i4 += 1024) {
        float4 v = make_float4(0.f, 0.f, 0.f, 0.f);
        if (i4 + 3 >= bl && i4 <= t) {
            const float4 r = *(const float4*)&arow[i4];
            v.x = (i4 + 0 >= bl && i4 + 0 <= t) ? __expf(r.x - m) * idv : 0.f;
            v.y = (i4 + 1 >= bl && i4 + 1 <= t) ? __expf(r.y - m) * idv : 0.f;
            v.z = (i4 + 2 >= bl && i4 + 2 <= t) ? __expf(r.z - m) * idv : 0.f;
            v.w = (i4 + 3 >= bl && i4 + 3 <= t) ? __expf(r.w - m) * idv : 0.f;
        }
        *(float4*)&arow[i4] = v;
    }
}

extern "C" void kernel_launch(void* const* d_in, const int* in_sizes, int n_in,
                              void* d_out, int out_size, void* d_ws, size_t ws_size,
                              hipStream_t stream) {
    const float* x     = (const float*)d_in[0];
    const float* Wq    = (const float*)d_in[1];
    const float* Wk    = (const float*)d_in[2];
    const float* Wv    = (const float*)d_in[3];
    const float* Wo    = (const float*)d_in[4];
    const float* gates = (const float*)d_in[5];
    const float* u     = (const float*)d_in[6];

    float* out  = (float*)d_out;                       // [T, E]
    float* attn = out + (size_t)T_LEN * EMB;           // [H, T, T]

    float* ws = (float*)d_ws;
    float* Qb = ws;
    float* Kb = Qb + (size_t)T_LEN * EMB;
    float* Vb = Kb + (size_t)T_LEN * EMB;
    float* Cb = Vb + (size_t)T_LEN * EMB;
    float* Db = Cb + (size_t)T_LEN * EMB;              // d bias [H, T]
    float* Mb = Db + (size_t)NH * T_LEN;               // row max [H, T]
    float* Ib = Mb + (size_t)NH * T_LEN;               // row 1/den [H, T]

    dim3 gg(EMB / 64, T_LEN / 64);
    gemm_f32_64x64<<<gg, 256, 0, stream>>>(x, Wq, Qb, T_LEN, EMB, EMB);
    gemm_f32_64x64<<<gg, 256, 0, stream>>>(x, Wk, Kb, T_LEN, EMB, EMB);
    gemm_f32_64x64<<<gg, 256, 0, stream>>>(x, Wv, Vb, T_LEN, EMB, EMB);
    dbias_kernel<<<NH, 256, 0, stream>>>(Kb, u, Db);

    attn_band_kernel<<<dim3(T_LEN / 64, NH), 256, 0, stream>>>(Qb, Kb, Vb, Db, gates,
                                                               attn, Cb, Mb, Ib);
    attn_norm_kernel<<<dim3(T_LEN, NH), 256, 0, stream>>>(attn, Mb, Ib);

    gemm_f32_64x64<<<gg, 256, 0, stream>>>(Cb, Wo, out, T_LEN, EMB, EMB);
}